// Round 12
// baseline (237.000 us; speedup 1.0000x reference)
//
#include <hip/hip_runtime.h>
#include <hip/hip_bf16.h>

#define B_ 2
#define T_ 2048
#define D_ 2048
#define NH_ 16
#define NKV_ 4
#define HD_ 128

using bf16 = __bf16;
using bf16x8 = __attribute__((ext_vector_type(8))) __bf16;
using bf16x4 = __attribute__((ext_vector_type(4))) __bf16;
using f32x4 = __attribute__((ext_vector_type(4))) float;

__device__ __forceinline__ void gld_lds16(bf16* lds, const bf16* g) {
  __builtin_amdgcn_global_load_lds(
      (const __attribute__((address_space(1))) void*)g,
      (__attribute__((address_space(3))) void*)lds, 16, 0, 0);
}

// ---------------- fused f32 -> bf16 convert (all 5 tensors, 1 launch) ---------
// segments (in 256-thread blocks of float4): x 8192 | wq 4096 | wk 1024 | wv 1024 | wo 4096
__global__ __launch_bounds__(256) void cvt_all(const float* __restrict__ x,
                                               const float* __restrict__ wq,
                                               const float* __restrict__ wk,
                                               const float* __restrict__ wv,
                                               const float* __restrict__ wo,
                                               bf16* __restrict__ xb,
                                               bf16* __restrict__ wqkvb,
                                               bf16* __restrict__ wob) {
  const int bid = blockIdx.x;
  const float* src;
  bf16* dst;
  int base;
  if (bid < 8192)       { src = x;  dst = xb;              base = bid; }
  else if (bid < 12288) { src = wq; dst = wqkvb;           base = bid - 8192; }
  else if (bid < 13312) { src = wk; dst = wqkvb + 4194304; base = bid - 12288; }
  else if (bid < 14336) { src = wv; dst = wqkvb + 5242880; base = bid - 13312; }
  else                  { src = wo; dst = wob;             base = bid - 14336; }
  const int i = base * 256 + threadIdx.x;
  float4 v = ((const float4*)src)[i];
  bf16x4 o;
  o[0] = (bf16)v.x; o[1] = (bf16)v.y; o[2] = (bf16)v.z; o[3] = (bf16)v.w;
  ((bf16x4*)dst)[i] = o;
}

// ---------------- GEMM: C[M,N] = A[M,K] * Bt[N,K]^T ----------------
// 128x128 tile, BK=32, 256 threads (4 waves, 2x2), mfma 16x16x32 bf16.
// Triple-buffered LDS (48KB) + counted vmcnt(4) + raw s_barrier (1/K-step).
template<typename OutT>
__global__ __launch_bounds__(256) void gemm_bt(const bf16* __restrict__ A,
                                               const bf16* __restrict__ Bt,
                                               OutT* __restrict__ C,
                                               int M, int N, int K) {
  __shared__ bf16 As[3][128 * 32];
  __shared__ bf16 Bs[3][128 * 32];
  const int tid = threadIdx.x;
  const int wid = tid >> 6;
  const int lane = tid & 63;
  const int g = lane >> 4, r = lane & 15;
  const int wm = wid >> 1, wn = wid & 1;
  const int gx = gridDim.x;
  const int nwg = gx * gridDim.y;
  const int flat = blockIdx.y * gx + blockIdx.x;
  const int swz = (flat & 7) * (nwg >> 3) + (flat >> 3);
  const long bm = (long)(swz / gx) * 128, bn = (long)(swz % gx) * 128;
  f32x4 acc[4][4] = {};
  const int NT = K >> 5;

  auto stage = [&](int buf, int k0) {
    for (int c = 0; c < 2; ++c) {
      int ch = wid * 2 + c;
      int row = ch * 16 + (lane >> 2);
      int col = (lane & 3) * 8;
      gld_lds16(&As[buf][ch * 512], A + (bm + row) * K + k0 + col);
      gld_lds16(&Bs[buf][ch * 512], Bt + (bn + row) * K + k0 + col);
    }
  };

  stage(0, 0);
  stage(1, 32);
  for (int t = 0; t < NT; ++t) {
    if (t + 1 < NT)
      asm volatile("s_waitcnt vmcnt(4)" ::: "memory");
    else
      asm volatile("s_waitcnt vmcnt(0)" ::: "memory");
    __builtin_amdgcn_s_barrier();
    if (t + 2 < NT) stage((t + 2) % 3, (t + 2) * 32);
    const bf16* as = As[t % 3];
    const bf16* bs = Bs[t % 3];
    bf16x8 af[4], bfr[4];
    for (int m = 0; m < 4; ++m)
      af[m] = *(const bf16x8*)(as + (wm * 64 + m * 16 + r) * 32 + g * 8);
    for (int n = 0; n < 4; ++n)
      bfr[n] = *(const bf16x8*)(bs + (wn * 64 + n * 16 + r) * 32 + g * 8);
    for (int m = 0; m < 4; ++m)
      for (int n = 0; n < 4; ++n)
        acc[m][n] = __builtin_amdgcn_mfma_f32_16x16x32_bf16(af[m], bfr[n], acc[m][n], 0, 0, 0);
  }

  for (int m = 0; m < 4; ++m)
    for (int n = 0; n < 4; ++n)
      for (int e = 0; e < 4; ++e) {
        long row = bm + wm * 64 + m * 16 + g * 4 + e;
        long col = bn + wn * 64 + n * 16 + r;
        C[row * N + col] = (OutT)acc[m][n][e];
      }
}

// ---------------- fused K RMSNorm+RoPE + V transpose (one launch) ----------------
// blocks [0,4096): K rows -> Kb [B][NKV][T][HD]; [4096,4608): V -> Vt [B][NKV][HD][T].
__global__ __launch_bounds__(256) void prep_kv(const bf16* __restrict__ qkv,
                                               const float* __restrict__ kw,
                                               bf16* __restrict__ Kb,
                                               bf16* __restrict__ Vt) {
  __shared__ float tile[64][65];
  const int bid = blockIdx.x;
  if (bid < 4096) {
    const int lane = threadIdx.x & 63;
    const int rloc = threadIdx.x >> 6;
    const long rid = (long)bid * 4 + rloc;
    const int h = (int)(rid % NKV_);
    const long bt = rid / NKV_;  // b*T + t
    const int t = (int)(bt % T_);
    const bf16* src = qkv + bt * 3072 + 2048 + h * HD_;
    float v0 = (float)src[lane];
    float v1 = (float)src[lane + 64];
    float ss = v0 * v0 + v1 * v1;
    for (int o = 1; o < 64; o <<= 1) ss += __shfl_xor(ss, o, 64);
    float inv = rsqrtf(ss * (1.f / HD_) + 1e-6f);
    float n0 = v0 * inv * kw[lane];
    float n1 = v1 * inv * kw[lane + 64];
    float ang = (float)t * exp2f((float)lane * (-13.287712379549449f / 64.f));
    float sv, cv;
    __sincosf(ang, &sv, &cv);
    long b = bt / T_;
    bf16* dst = Kb + ((b * NKV_ + h) * (long)T_ + t) * HD_;
    dst[lane] = (bf16)(n0 * cv - n1 * sv);
    dst[lane + 64] = (bf16)(n1 * cv + n0 * sv);
  } else {
    const int bid2 = bid - 4096;
    const int tt = bid2 & 31;
    const int by = bid2 >> 5;
    const int dd = by & 1;
    const int bkv = by >> 1;
    const long b = bkv >> 2;
    const int kv = bkv & 3;
    const int t0 = tt * 64, d0 = dd * 64;
    for (int i = 0; i < 2; ++i) {
      int row = i * 32 + (threadIdx.x >> 3);
      int c8 = (threadIdx.x & 7) * 8;
      bf16x8 v = *(const bf16x8*)&qkv[(b * T_ + t0 + row) * 3072 + 2560 + kv * HD_ + d0 + c8];
      for (int j = 0; j < 8; ++j) tile[row][c8 + j] = (float)v[j];
    }
    __syncthreads();
    for (int i = 0; i < 2; ++i) {
      int drow = i * 32 + (threadIdx.x >> 3);
      int tc8 = (threadIdx.x & 7) * 8;
      bf16x8 o;
      for (int j = 0; j < 8; ++j) o[j] = (bf16)tile[tc8 + j][drow];
      *(bf16x8*)&Vt[((b * NKV_ + kv) * (long)HD_ + d0 + drow) * T_ + t0 + tc8] = o;
    }
  }
}

// ---------------- causal GQA flash attention: 32-waves/CU k-split structure ----
// Round 12: 64 q-rows / 8 waves per block; wave wid = (fragment f=wid>>1 of 16
// q-rows, group gr=wid&1). Groups split each 64-k tile: gr covers k in
// [k0+32gr, k0+32gr+32) -> PV contraction K=32 = exactly one MFMA, no waste.
// K/V SINGLE-buffered: LDS = Ks 16KB + Vs 16KB + Ps 8KB = 40KB -> 4 blocks/CU;
// grid (32,16,2)=1024 blocks = exactly 4/CU resident -> up to 32 waves/CU
// (TLP is the proven lever: 8w=137us, 16w=78.5us). Staging latency is exposed
// per tile (no double buffer) but hidden across the 4 co-resident blocks.
// Per-group online softmax; groups merged once at block end via LDS overlay
// (round-10 merge math + mden guard for fully-masked group rows).
// Quad-residency balance: slots {i,i+256,i+512,i+768} = same x, (y8,z) all 4
// combos; qt map below gives constant quad work-sum (62+4 tiles).
__global__ __launch_bounds__(512) void flash_attn(const bf16* __restrict__ QKV,
                                                  const float* __restrict__ qw,
                                                  const bf16* __restrict__ K,
                                                  const bf16* __restrict__ V,
                                                  bf16* __restrict__ O) {
  __shared__ char smem[40960];
  bf16* Ks = (bf16*)smem;             // [64][128] swizzled, 16KB
  bf16* Vs = (bf16*)(smem + 16384);   // [128][64] swizzled, 16KB
  bf16* Ps = (bf16*)(smem + 32768);   // 8 waves x [16][32] swizzled, 8KB
  float* mergeO = (float*)smem;       // epilogue overlay: 4 frags x 16 x 128 f32 = 32KB
  float* mergeML = (float*)(smem + 32768);  // epilogue overlay: 4 x 32 f32

  const int h = blockIdx.y, b = blockIdx.z;
  const int x = blockIdx.x;
  const int y8 = (h >> 3) & 1;
  // constant quad-sum qt map: (y8,z)=(0,0):31-x (1,0):x (0,1):x^1 (1,1):31-(x^1)
  const int qt = b ? (y8 ? 31 - (x ^ 1) : (x ^ 1)) : (y8 ? x : 31 - x);
  const int kv = h >> 2;
  const int tid = threadIdx.x, wid = tid >> 6, lane = tid & 63;
  const int g = lane >> 4, r = lane & 15;
  const int f = wid >> 1;           // q fragment 0..3
  const int gr = wid & 1;           // k group 0..1
  const int ko = gr * 32;           // group k offset within tile
  const int q0 = qt * 64;
  const int qbase = q0 + f * 16;    // wave-uniform
  const int q = qbase + r;          // this lane's q-row

  // ---- fused Q RMSNorm + RoPE prologue (both group waves load same Q rows) ----
  const bf16* qsrc = QKV + ((long)(b * T_ + q)) * 3072 + h * HD_;
  float ssq = 0.f;
  for (int kk = 0; kk < 4; ++kk) {
    bf16x8 tq = *(const bf16x8*)(qsrc + kk * 32 + g * 8);
    for (int j = 0; j < 8; ++j) { float ff = (float)tq[j]; ssq += ff * ff; }
  }
  ssq += __shfl_xor(ssq, 16, 64);
  ssq += __shfl_xor(ssq, 32, 64);
  const float qinv = rsqrtf(ssq * (1.f / HD_) + 1e-6f);
  bf16x8 aq[4];
  for (int kk = 0; kk < 2; ++kk) {
    bf16x8 tlo = *(const bf16x8*)(qsrc + kk * 32 + g * 8);
    bf16x8 thi = *(const bf16x8*)(qsrc + kk * 32 + 64 + g * 8);
    bf16x8 alo, ahi;
    for (int j = 0; j < 8; ++j) {
      const int d = kk * 32 + g * 8 + j;
      float n0 = (float)tlo[j] * qinv * qw[d];
      float n1 = (float)thi[j] * qinv * qw[d + 64];
      float ang = (float)q * exp2f((float)d * (-13.287712379549449f / 64.f));
      float sv, cv;
      __sincosf(ang, &sv, &cv);
      alo[j] = (bf16)(n0 * cv - n1 * sv);
      ahi[j] = (bf16)(n1 * cv + n0 * sv);
    }
    aq[kk] = alo;
    aq[kk + 2] = ahi;
  }

  f32x4 oacc[8] = {};
  float m_run = -1e30f, l_run = 0.f;

  const bf16* Kbase = K + ((long)(b * NKV_ + kv)) * T_ * HD_;
  const bf16* Vbase = V + ((long)(b * NKV_ + kv)) * (long)HD_ * T_;
  const int nkt = qt + 1;  // k-tiles of 64 covering [0, q0+64)

  // stage full K tile (16 chunks) + V^T tile (16 chunks): 2+2 chunks per wave
  auto stageKV = [&](int k0) {
    for (int c = 0; c < 2; ++c) {
      int ch = wid * 2 + c;
      {
        int row = ch * 4 + (lane >> 4);
        int srccol = ((lane & 15) ^ (row & 7)) * 8;
        gld_lds16(&Ks[ch * 512], Kbase + (long)(k0 + row) * HD_ + srccol);
      }
      {
        int row = ch * 8 + (lane >> 3);
        int srccol = ((lane & 7) ^ (row & 7)) * 8;
        gld_lds16(&Vs[ch * 512], Vbase + (long)row * T_ + k0 + srccol);
      }
    }
  };

  const float scale = 0.088388347648318447f;  // 1/sqrt(128)
  bf16* myPs = Ps + wid * 512;                // [16][32]

  stageKV(0);
  for (int kt = 0; kt < nkt; ++kt) {
    const int k0 = kt * 64;
    asm volatile("s_waitcnt vmcnt(0)" ::: "memory");
    __builtin_amdgcn_s_barrier();   // tile visible to all waves

    // S^T = K * Q^T over this group's 32 k: lane (g,r) holds
    // S[k = k0+ko+n*16+g*4+e][q], n in {0,1}
    f32x4 s[2] = {};
    __builtin_amdgcn_s_setprio(1);
    for (int n = 0; n < 2; ++n)
      for (int kk = 0; kk < 4; ++kk) {
        int row = ko + n * 16 + r;
        bf16x8 bk = *(const bf16x8*)(&Ks[row * 128 + (((kk * 4 + g) ^ (row & 7)) * 8)]);
        s[n] = __builtin_amdgcn_mfma_f32_16x16x32_bf16(bk, aq[kk], s[n], 0, 0, 0);
      }
    __builtin_amdgcn_s_setprio(0);

    // per-lane softmax over 8 k-values
    const bool domask = (k0 + ko + 31 > qbase);  // wave-uniform
    float mx = -1e30f;
    if (domask) {
      for (int n = 0; n < 2; ++n) {
        const int km = k0 + ko + n * 16 + g * 4;
        for (int e = 0; e < 4; ++e) {
          float v = s[n][e] * scale;
          if (km + e > q) v = -1e30f;
          s[n][e] = v;
          mx = fmaxf(mx, v);
        }
      }
    } else {
      for (int n = 0; n < 2; ++n)
        for (int e = 0; e < 4; ++e) {
          float v = s[n][e] * scale;
          s[n][e] = v;
          mx = fmaxf(mx, v);
        }
    }
    mx = fmaxf(mx, __shfl_xor(mx, 16, 64));
    mx = fmaxf(mx, __shfl_xor(mx, 32, 64));
    float mnew = fmaxf(m_run, mx);
    float alpha = __expf(m_run - mnew);
    // guard: fully-masked rows (mnew = -1e30) must produce p = 0, not exp(0).
    const float mden = fmaxf(mnew, -1e28f);
    float ls = 0.f;
    for (int n = 0; n < 2; ++n) {
      bf16x4 pb;
      for (int e = 0; e < 4; ++e) {
        float p = __expf(s[n][e] - mden);
        ls += p;
        pb[e] = (bf16)p;
      }
      // col base = n*16+g*4 -> 8-wide col-group c = n*2+(g>>1), offset (g&1)*4
      int c = n * 2 + (g >> 1);
      *(bf16x4*)(&myPs[r * 32 + ((c ^ (r & 3)) * 8) + (g & 1) * 4]) = pb;
    }
    ls += __shfl_xor(ls, 16, 64);
    ls += __shfl_xor(ls, 32, 64);
    m_run = mnew;
    l_run = l_run * alpha + ls;

    // broadcast alpha to oacc row layout (row = g*4+e held by lane with r==row)
    float al[4];
    for (int e = 0; e < 4; ++e)
      al[e] = __shfl(alpha, (lane & 48) | (g * 4 + e), 64);
    for (int dt = 0; dt < 8; ++dt)
      for (int e = 0; e < 4; ++e) oacc[dt][e] *= al[e];

    asm volatile("s_waitcnt lgkmcnt(0)" ::: "memory");  // own-wave Ps visible

    // O += P(group) * V(group's 32 k): one MFMA per 16-d tile
    __builtin_amdgcn_s_setprio(1);
    {
      bf16x8 ap = *(const bf16x8*)(&myPs[r * 32 + ((g ^ (r & 3)) * 8)]);
      for (int dt = 0; dt < 8; ++dt) {
        int row = dt * 16 + r;
        bf16x8 bv = *(const bf16x8*)(&Vs[row * 64 + (((gr * 4 + g) ^ (row & 7)) * 8)]);
        oacc[dt] = __builtin_amdgcn_mfma_f32_16x16x32_bf16(ap, bv, oacc[dt], 0, 0, 0);
      }
    }
    __builtin_amdgcn_s_setprio(0);
    __builtin_amdgcn_s_barrier();   // all waves done reading Ks/Vs
    if (kt + 1 < nkt) stageKV(k0 + 64);
  }

  // ---- merge the two k-groups per fragment, write O ----
  if (gr == 1) {
    float* mo = mergeO + f * 2048;   // [16][128]
    for (int e = 0; e < 4; ++e)
      for (int dt = 0; dt < 8; ++dt)
        mo[(g * 4 + e) * 128 + dt * 16 + r] = oacc[dt][e];
    if (g == 0) {
      mergeML[f * 32 + r] = m_run;
      mergeML[f * 32 + 16 + r] = l_run;
    }
  }
  __syncthreads();
  if (gr == 0) {
    const float* mo = mergeO + f * 2048;
    const float m1 = mergeML[f * 32 + r];
    const float l1 = mergeML[f * 32 + 16 + r];
    const float M = fmaxf(m_run, m1);
    const float w0 = __expf(m_run - M);
    const float w1 = __expf(m1 - M);
    const float lt = l_run * w0 + l1 * w1;
    float W0[4], W1[4], LI[4];
    for (int e = 0; e < 4; ++e) {
      const int src = (lane & 48) | (g * 4 + e);
      W0[e] = __shfl(w0, src, 64);
      W1[e] = __shfl(w1, src, 64);
      LI[e] = 1.f / __shfl(lt, src, 64);
    }
    for (int e = 0; e < 4; ++e) {
      const int grow = qbase + g * 4 + e;
      bf16* dst = O + ((long)(b * T_ + grow)) * (NH_ * HD_) + h * HD_;
      for (int dt = 0; dt < 8; ++dt) {
        float o1 = mo[(g * 4 + e) * 128 + dt * 16 + r];
        dst[dt * 16 + r] = (bf16)((oacc[dt][e] * W0[e] + o1 * W1[e]) * LI[e]);
      }
    }
  }
}

extern "C" void kernel_launch(void* const* d_in, const int* in_sizes, int n_in,
                              void* d_out, int out_size, void* d_ws, size_t ws_size,
                              hipStream_t stream) {
  const float* x  = (const float*)d_in[0];
  const float* wq = (const float*)d_in[1];
  const float* wk = (const float*)d_in[2];
  const float* wv = (const float*)d_in[3];
  const float* wo = (const float*)d_in[4];
  const float* qw = (const float*)d_in[5];
  const float* kw = (const float*)d_in[6];
  float* out = (float*)d_out;

  char* p = (char*)d_ws;
  bf16* xb    = (bf16*)(p);                 // 16 MB  [4096][2048]
  bf16* wqkvb = (bf16*)(p + 16777216);      // 12 MB  [3072][2048] (wq|wk|wv)
  bf16* wob   = (bf16*)(p + 29360128);      //  8 MB  [2048][2048]
  bf16* QKVr  = (bf16*)(p + 37748736);      // 24 MB  [4096][3072]
  bf16* Kb    = (bf16*)(p + 79691776);      //  4 MB  [B][NKV][T][HD]
  bf16* Vt    = (bf16*)(p + 83886080);      //  4 MB  [B][NKV][HD][T]
  bf16* attb  = (bf16*)(p + 88080384);      // 16 MB  [4096][2048]

  cvt_all<<<18432, 256, 0, stream>>>(x, wq, wk, wv, wo, xb, wqkvb, wob);

  // fused QKV projection: [4096][2048] x [3072][2048]^T -> [4096][3072]
  gemm_bt<bf16><<<dim3(24, 32), 256, 0, stream>>>(xb, wqkvb, QKVr, 4096, 3072, 2048);

  prep_kv<<<4608, 256, 0, stream>>>(QKVr, kw, Kb, Vt);

  flash_attn<<<dim3(32, 16, 2), 512, 0, stream>>>(QKVr, qw, Kb, Vt, attb);

  gemm_bt<float><<<dim3(16, 32), 256, 0, stream>>>(attb, wob, out, 4096, 2048, 2048);
}

// Round 13
// 207.206 us; speedup vs baseline: 1.1438x; 1.1438x over previous
//
#include <hip/hip_runtime.h>
#include <hip/hip_bf16.h>

#define B_ 2
#define T_ 2048
#define D_ 2048
#define NH_ 16
#define NKV_ 4
#define HD_ 128

using bf16 = __bf16;
using bf16x8 = __attribute__((ext_vector_type(8))) __bf16;
using bf16x4 = __attribute__((ext_vector_type(4))) __bf16;
using f32x4 = __attribute__((ext_vector_type(4))) float;

__device__ __forceinline__ void gld_lds16(bf16* lds, const bf16* g) {
  __builtin_amdgcn_global_load_lds(
      (const __attribute__((address_space(1))) void*)g,
      (__attribute__((address_space(3))) void*)lds, 16, 0, 0);
}

// ---------------- fused f32 -> bf16 convert (all 5 tensors, 1 launch) ---------
// segments (in 256-thread blocks of float4): x 8192 | wq 4096 | wk 1024 | wv 1024 | wo 4096
__global__ __launch_bounds__(256) void cvt_all(const float* __restrict__ x,
                                               const float* __restrict__ wq,
                                               const float* __restrict__ wk,
                                               const float* __restrict__ wv,
                                               const float* __restrict__ wo,
                                               bf16* __restrict__ xb,
                                               bf16* __restrict__ wqkvb,
                                               bf16* __restrict__ wob) {
  const int bid = blockIdx.x;
  const float* src;
  bf16* dst;
  int base;
  if (bid < 8192)       { src = x;  dst = xb;              base = bid; }
  else if (bid < 12288) { src = wq; dst = wqkvb;           base = bid - 8192; }
  else if (bid < 13312) { src = wk; dst = wqkvb + 4194304; base = bid - 12288; }
  else if (bid < 14336) { src = wv; dst = wqkvb + 5242880; base = bid - 13312; }
  else                  { src = wo; dst = wob;             base = bid - 14336; }
  const int i = base * 256 + threadIdx.x;
  float4 v = ((const float4*)src)[i];
  bf16x4 o;
  o[0] = (bf16)v.x; o[1] = (bf16)v.y; o[2] = (bf16)v.z; o[3] = (bf16)v.w;
  ((bf16x4*)dst)[i] = o;
}

// ---------------- GEMM: C[M,N] = A[M,K] * Bt[N,K]^T ----------------
// 128x128 tile, BK=32, 256 threads (4 waves, 2x2), mfma 16x16x32 bf16.
// Triple-buffered LDS (48KB) + counted vmcnt(4) + raw s_barrier (1/K-step).
// Stage t+2 after barrier t; target buf (t-1)%3 safe (readers retired before
// the barrier). vmcnt(4) drains only stage(t), keeps stage(t+1) in flight.
// XCD-aware bijective block swizzle (grid size must be %8==0 — it is).
template<typename OutT>
__global__ __launch_bounds__(256) void gemm_bt(const bf16* __restrict__ A,
                                               const bf16* __restrict__ Bt,
                                               OutT* __restrict__ C,
                                               int M, int N, int K) {
  __shared__ bf16 As[3][128 * 32];
  __shared__ bf16 Bs[3][128 * 32];
  const int tid = threadIdx.x;
  const int wid = tid >> 6;
  const int lane = tid & 63;
  const int g = lane >> 4, r = lane & 15;
  const int wm = wid >> 1, wn = wid & 1;
  const int gx = gridDim.x;
  const int nwg = gx * gridDim.y;
  const int flat = blockIdx.y * gx + blockIdx.x;
  const int swz = (flat & 7) * (nwg >> 3) + (flat >> 3);
  const long bm = (long)(swz / gx) * 128, bn = (long)(swz % gx) * 128;
  f32x4 acc[4][4] = {};
  const int NT = K >> 5;

  auto stage = [&](int buf, int k0) {
    for (int c = 0; c < 2; ++c) {
      int ch = wid * 2 + c;
      int row = ch * 16 + (lane >> 2);
      int col = (lane & 3) * 8;
      gld_lds16(&As[buf][ch * 512], A + (bm + row) * K + k0 + col);
      gld_lds16(&Bs[buf][ch * 512], Bt + (bn + row) * K + k0 + col);
    }
  };

  stage(0, 0);
  stage(1, 32);
  for (int t = 0; t < NT; ++t) {
    if (t + 1 < NT)
      asm volatile("s_waitcnt vmcnt(4)" ::: "memory");  // stage(t) done, stage(t+1) in flight
    else
      asm volatile("s_waitcnt vmcnt(0)" ::: "memory");
    __builtin_amdgcn_s_barrier();
    if (t + 2 < NT) stage((t + 2) % 3, (t + 2) * 32);
    const bf16* as = As[t % 3];
    const bf16* bs = Bs[t % 3];
    bf16x8 af[4], bfr[4];
    for (int m = 0; m < 4; ++m)
      af[m] = *(const bf16x8*)(as + (wm * 64 + m * 16 + r) * 32 + g * 8);
    for (int n = 0; n < 4; ++n)
      bfr[n] = *(const bf16x8*)(bs + (wn * 64 + n * 16 + r) * 32 + g * 8);
    for (int m = 0; m < 4; ++m)
      for (int n = 0; n < 4; ++n)
        acc[m][n] = __builtin_amdgcn_mfma_f32_16x16x32_bf16(af[m], bfr[n], acc[m][n], 0, 0, 0);
  }

  for (int m = 0; m < 4; ++m)
    for (int n = 0; n < 4; ++n)
      for (int e = 0; e < 4; ++e) {
        long row = bm + wm * 64 + m * 16 + g * 4 + e;
        long col = bn + wn * 64 + n * 16 + r;
        C[row * N + col] = (OutT)acc[m][n][e];
      }
}

// ---------------- fused K RMSNorm+RoPE + V transpose (one launch) ----------------
// blocks [0,4096): K rows -> Kb [B][NKV][T][HD]; [4096,4608): V -> Vt [B][NKV][HD][T].
__global__ __launch_bounds__(256) void prep_kv(const bf16* __restrict__ qkv,
                                               const float* __restrict__ kw,
                                               bf16* __restrict__ Kb,
                                               bf16* __restrict__ Vt) {
  __shared__ float tile[64][65];
  const int bid = blockIdx.x;
  if (bid < 4096) {
    const int lane = threadIdx.x & 63;
    const int rloc = threadIdx.x >> 6;
    const long rid = (long)bid * 4 + rloc;
    const int h = (int)(rid % NKV_);
    const long bt = rid / NKV_;  // b*T + t
    const int t = (int)(bt % T_);
    const bf16* src = qkv + bt * 3072 + 2048 + h * HD_;
    float v0 = (float)src[lane];
    float v1 = (float)src[lane + 64];
    float ss = v0 * v0 + v1 * v1;
    for (int o = 1; o < 64; o <<= 1) ss += __shfl_xor(ss, o, 64);
    float inv = rsqrtf(ss * (1.f / HD_) + 1e-6f);
    float n0 = v0 * inv * kw[lane];
    float n1 = v1 * inv * kw[lane + 64];
    float ang = (float)t * exp2f((float)lane * (-13.287712379549449f / 64.f));
    float sv, cv;
    __sincosf(ang, &sv, &cv);
    long b = bt / T_;
    bf16* dst = Kb + ((b * NKV_ + h) * (long)T_ + t) * HD_;
    dst[lane] = (bf16)(n0 * cv - n1 * sv);
    dst[lane + 64] = (bf16)(n1 * cv + n0 * sv);
  } else {
    const int bid2 = bid - 4096;
    const int tt = bid2 & 31;
    const int by = bid2 >> 5;
    const int dd = by & 1;
    const int bkv = by >> 1;
    const long b = bkv >> 2;
    const int kv = bkv & 3;
    const int t0 = tt * 64, d0 = dd * 64;
    for (int i = 0; i < 2; ++i) {
      int row = i * 32 + (threadIdx.x >> 3);
      int c8 = (threadIdx.x & 7) * 8;
      bf16x8 v = *(const bf16x8*)&qkv[(b * T_ + t0 + row) * 3072 + 2560 + kv * HD_ + d0 + c8];
      for (int j = 0; j < 8; ++j) tile[row][c8 + j] = (float)v[j];
    }
    __syncthreads();
    for (int i = 0; i < 2; ++i) {
      int drow = i * 32 + (threadIdx.x >> 3);
      int tc8 = (threadIdx.x & 7) * 8;
      bf16x8 o;
      for (int j = 0; j < 8; ++j) o[j] = (bf16)tile[tc8 + j][drow];
      *(bf16x8*)&Vt[((b * NKV_ + kv) * (long)HD_ + d0 + drow) * T_ + t0 + tc8] = o;
    }
  }
}

// ---------------- causal GQA flash attention (swapped QK^T, per-lane softmax) ----
// Round 13: verbatim restore of the measured optimum (round 8/11, 207.2 us,
// reproduced twice). 8 waves / 128 q-rows, 80KB LDS double-buffered K/V,
// 16 waves/CU. Structure-family search complete: 4-wave blocks (r3: 137us),
// 2-fragment waves (r7: 137us), adjacent pairing (r9: 108us), equal-work
// split+merge (r10: 91us), k-split 4-block single-buffer (r12: 115us) all
// measured worse. Reverse qt pairing = min-max optimal bijective pairing
// under the shared-rate model (paired phase at R16, solo at R16/1.45).
// Q RMSNorm+RoPE fused in prologue (reads QKVr directly).
__global__ __launch_bounds__(512) void flash_attn(const bf16* __restrict__ QKV,
                                                  const float* __restrict__ qw,
                                                  const bf16* __restrict__ K,
                                                  const bf16* __restrict__ V,
                                                  bf16* __restrict__ O) {
  __shared__ bf16 Ks[2][64 * 128];   // [k][d], swizzled
  __shared__ bf16 Vs[2][128 * 64];   // [d][k], swizzled
  __shared__ bf16 Ps[8][16 * 64];    // per-wave P tile [q][k], swizzled
  const int h = blockIdx.y, b = blockIdx.z;
  const int qt = b ? blockIdx.x : (gridDim.x - 1) - blockIdx.x;  // pair long+short per CU
  const int kv = h >> 2;
  const int tid = threadIdx.x, wid = tid >> 6, lane = tid & 63;
  const int g = lane >> 4, r = lane & 15;
  const int q0 = qt * 128;
  const int qbase = q0 + wid * 16;      // wave-uniform
  const int q = qbase + r;              // this lane's q-row (softmax ownership)

  // ---- fused Q RMSNorm + RoPE prologue (replaces Qb round-trip) ----
  // lane holds dims kk*32+g*8+j; RoPE pairs (d, d+64) = (aq[0],aq[2]),(aq[1],aq[3]).
  const bf16* qsrc = QKV + ((long)(b * T_ + q)) * 3072 + h * HD_;
  float ss = 0.f;
  for (int kk = 0; kk < 4; ++kk) {
    bf16x8 tq = *(const bf16x8*)(qsrc + kk * 32 + g * 8);
    for (int j = 0; j < 8; ++j) { float f = (float)tq[j]; ss += f * f; }
  }
  ss += __shfl_xor(ss, 16, 64);
  ss += __shfl_xor(ss, 32, 64);
  const float inv = rsqrtf(ss * (1.f / HD_) + 1e-6f);
  bf16x8 aq[4];
  for (int kk = 0; kk < 2; ++kk) {
    bf16x8 tlo = *(const bf16x8*)(qsrc + kk * 32 + g * 8);        // L1-hot reload
    bf16x8 thi = *(const bf16x8*)(qsrc + kk * 32 + 64 + g * 8);
    bf16x8 alo, ahi;
    for (int j = 0; j < 8; ++j) {
      const int d = kk * 32 + g * 8 + j;
      float n0 = (float)tlo[j] * inv * qw[d];
      float n1 = (float)thi[j] * inv * qw[d + 64];
      float ang = (float)q * exp2f((float)d * (-13.287712379549449f / 64.f));
      float sv, cv;
      __sincosf(ang, &sv, &cv);
      alo[j] = (bf16)(n0 * cv - n1 * sv);
      ahi[j] = (bf16)(n1 * cv + n0 * sv);
    }
    aq[kk] = alo;
    aq[kk + 2] = ahi;
  }

  f32x4 oacc[8] = {};
  float m_run = -1e30f, l_run = 0.f;

  const bf16* Kbase = K + ((long)(b * NKV_ + kv)) * T_ * HD_;
  const bf16* Vbase = V + ((long)(b * NKV_ + kv)) * (long)HD_ * T_;
  const int nkt = 2 * qt + 2;

  // stage K (16 chunks of 1KB) + V^T (16 chunks): 2+2 chunks per wave
  auto stageKV = [&](int buf, int k0) {
    for (int c = 0; c < 2; ++c) {
      int ch = wid * 2 + c;
      {
        int row = ch * 4 + (lane >> 4);
        int srccol = ((lane & 15) ^ (row & 7)) * 8;
        gld_lds16(&Ks[buf][ch * 512], Kbase + (long)(k0 + row) * HD_ + srccol);
      }
      {
        int row = ch * 8 + (lane >> 3);
        int srccol = ((lane & 7) ^ (row & 7)) * 8;
        gld_lds16(&Vs[buf][ch * 512], Vbase + (long)row * T_ + k0 + srccol);
      }
    }
  };

  stageKV(0, 0);
  for (int kt = 0; kt < nkt; ++kt) {
    const int k0 = kt * 64;
    const int cur = kt & 1;
    if (kt + 1 < nkt) {
      stageKV(cur ^ 1, k0 + 64);
      asm volatile("s_waitcnt vmcnt(4)" ::: "memory");  // drain current tile only
    } else {
      asm volatile("s_waitcnt vmcnt(0)" ::: "memory");
    }
    __builtin_amdgcn_s_barrier();

    // S^T = K * Q^T : lane (g,r) holds S[k=k0+n*16+g*4+e][q]
    f32x4 s[4] = {};
    __builtin_amdgcn_s_setprio(1);
    for (int n = 0; n < 4; ++n)
      for (int kk = 0; kk < 4; ++kk) {
        int row = n * 16 + r;
        bf16x8 bk = *(const bf16x8*)(&Ks[cur][row * 128 + (((kk * 4 + g) ^ (row & 7)) * 8)]);
        s[n] = __builtin_amdgcn_mfma_f32_16x16x32_bf16(bk, aq[kk], s[n], 0, 0, 0);
      }
    __builtin_amdgcn_s_setprio(0);

    // per-lane softmax over 16 k-values
    const float scale = 0.088388347648318447f;  // 1/sqrt(128)
    const bool domask = (k0 + 63 > qbase);      // wave-uniform
    float mx = -1e30f;
    if (domask) {
      for (int n = 0; n < 4; ++n) {
        const int km = k0 + n * 16 + g * 4;
        for (int e = 0; e < 4; ++e) {
          float v = s[n][e] * scale;
          if (km + e > q) v = -1e30f;
          s[n][e] = v;
          mx = fmaxf(mx, v);
        }
      }
    } else {
      for (int n = 0; n < 4; ++n)
        for (int e = 0; e < 4; ++e) {
          float v = s[n][e] * scale;
          s[n][e] = v;
          mx = fmaxf(mx, v);
        }
    }
    mx = fmaxf(mx, __shfl_xor(mx, 16, 64));
    mx = fmaxf(mx, __shfl_xor(mx, 32, 64));
    float mnew = fmaxf(m_run, mx);
    float alpha = __expf(m_run - mnew);
    float ls = 0.f;
    for (int n = 0; n < 4; ++n) {
      bf16x4 pb;
      for (int e = 0; e < 4; ++e) {
        float p = __expf(s[n][e] - mnew);
        ls += p;
        pb[e] = (bf16)p;
      }
      int c = n * 2 + (g >> 1);
      *(bf16x4*)(&Ps[wid][r * 64 + ((c ^ (r & 7)) * 8) + (g & 1) * 4]) = pb;
    }
    ls += __shfl_xor(ls, 16, 64);
    ls += __shfl_xor(ls, 32, 64);
    m_run = mnew;
    l_run = l_run * alpha + ls;

    // broadcast alpha to oacc row layout (row = g*4+e held by lane with r==row)
    float al[4];
    for (int e = 0; e < 4; ++e)
      al[e] = __shfl(alpha, (lane & 48) | (g * 4 + e), 64);
    for (int dt = 0; dt < 8; ++dt)
      for (int e = 0; e < 4; ++e) oacc[dt][e] *= al[e];

    asm volatile("s_waitcnt lgkmcnt(0)" ::: "memory");

    // O += P * V
    __builtin_amdgcn_s_setprio(1);
    for (int kk = 0; kk < 2; ++kk) {
      bf16x8 ap = *(const bf16x8*)(&Ps[wid][r * 64 + (((kk * 4 + g) ^ (r & 7)) * 8)]);
      for (int dt = 0; dt < 8; ++dt) {
        int row = dt * 16 + r;
        bf16x8 bv = *(const bf16x8*)(&Vs[cur][row * 64 + (((kk * 4 + g) ^ (row & 7)) * 8)]);
        oacc[dt] = __builtin_amdgcn_mfma_f32_16x16x32_bf16(ap, bv, oacc[dt], 0, 0, 0);
      }
    }
    __builtin_amdgcn_s_setprio(0);
    __builtin_amdgcn_s_barrier();  // protect buf cur before overwrite at kt+2
  }

  // final: redistribute l to oacc row layout, write O
  float li[4];
  for (int e = 0; e < 4; ++e) {
    float lv = __shfl(l_run, (lane & 48) | (g * 4 + e), 64);
    li[e] = 1.f / lv;
  }
  for (int e = 0; e < 4; ++e) {
    const int grow = q0 + wid * 16 + g * 4 + e;
    bf16* dst = O + ((long)(b * T_ + grow)) * (NH_ * HD_) + h * HD_;
    for (int dt = 0; dt < 8; ++dt)
      dst[dt * 16 + r] = (bf16)(oacc[dt][e] * li[e]);
  }
}

extern "C" void kernel_launch(void* const* d_in, const int* in_sizes, int n_in,
                              void* d_out, int out_size, void* d_ws, size_t ws_size,
                              hipStream_t stream) {
  const float* x  = (const float*)d_in[0];
  const float* wq = (const float*)d_in[1];
  const float* wk = (const float*)d_in[2];
  const float* wv = (const float*)d_in[3];
  const float* wo = (const float*)d_in[4];
  const float* qw = (const float*)d_in[5];
  const float* kw = (const float*)d_in[6];
  float* out = (float*)d_out;

  char* p = (char*)d_ws;
  bf16* xb    = (bf16*)(p);                 // 16 MB  [4096][2048]
  bf16* wqkvb = (bf16*)(p + 16777216);      // 12 MB  [3072][2048] (wq|wk|wv)
  bf16* wob   = (bf16*)(p + 29360128);      //  8 MB  [2048][2048]
  bf16* QKVr  = (bf16*)(p + 37748736);      // 24 MB  [4096][3072]
  bf16* Kb    = (bf16*)(p + 79691776);      //  4 MB  [B][NKV][T][HD]
  bf16* Vt    = (bf16*)(p + 83886080);      //  4 MB  [B][NKV][HD][T]
  bf16* attb  = (bf16*)(p + 88080384);      // 16 MB  [4096][2048]

  cvt_all<<<18432, 256, 0, stream>>>(x, wq, wk, wv, wo, xb, wqkvb, wob);

  // fused QKV projection: [4096][2048] x [3072][2048]^T -> [4096][3072]
  gemm_bt<bf16><<<dim3(24, 32), 256, 0, stream>>>(xb, wqkvb, QKVr, 4096, 3072, 2048);

  prep_kv<<<4608, 256, 0, stream>>>(QKVr, kw, Kb, Vt);

  flash_attn<<<dim3(16, 16, 2), 512, 0, stream>>>(QKVr, qw, Kb, Vt, attb);

  gemm_bt<float><<<dim3(16, 32), 256, 0, stream>>>(attb, wob, out, 4096, 2048, 2048);
}